// Round 16
// baseline (4380.077 us; speedup 1.0000x reference)
//
#include <hip/hip_runtime.h>
#include <math.h>

typedef float4 f4;
typedef unsigned long long u64;
#define NW 248
#define NB 64
#define NPH2 (NW + 8)   // 256 phases; phase p: L0 step p, L1 step p-1 (window-parallel, split 2 blocks/row)

// ============================================================================
// r14 mapping (1024-thread pair-split, correctness-verified) with the CORRECT
// occupancy knob: __launch_bounds__(1024, 4) -> min 4 waves/EU -> 1 block/CU
// -> 128-VGPR allocator cap. r14's amdgpu_waves_per_eu(4,4) was IGNORED (alloc
// provisioned 64 VGPR for 2 blocks/CU -> total spill, 314MB FETCH, 4242us).
// Working set here ~100-108 regs (QM=8) -> fits 128.
// Session failure catalog — do NOT retry:
//  - r8:  >1 spinner thread/block on agent atomics -> coherent-poll storm (16x).
//  - r10: 4 blocks/row -> exchange exposure doubles, 1692us.
//  - r11: RELAXED atomic spin-loads lower to per-poll writes (WRITE_SIZE 15MB).
//  - r11/r12: duplicated region-A code paths -> VGPR 128 + scratch spill.
//  - r13: producer-only bar1 / post-reordering: neutral-negative.
// Health checks this round: VGPR 104-126 + WRITE_SIZE ~1.5KB = knob worked;
// VGPR 64 or FETCH >>10MB = knob rejected -> revert to r9/r15 champion (912us).
// ============================================================================

__device__ __forceinline__ float tanh_f(float x) { return 2.0f * __builtin_amdgcn_rcpf(1.0f + __expf(-2.0f * x)) - 1.0f; }

template<int CTRL>
__device__ __forceinline__ float dppf(float v) {
    return __int_as_float(__builtin_amdgcn_update_dpp(0, __float_as_int(v), CTRL, 0xF, 0xF, true));
}
#define XOR1 0xB1   // quad_perm [1,0,3,2]
#define XOR2 0x4E   // quad_perm [2,3,0,1]
#define MIR7 0x141  // ROW_HALF_MIRROR: lane i -> 7-i within 8 (== xor 7)
#define BC0  0x00
#define BC1  0x55
#define BC2  0xAA
#define BC3  0xFF

#define OPQ1(X) asm volatile("" : "+v"(X));
#define OPQ4(V) OPQ1(V.x) OPQ1(V.y) OPQ1(V.z) OPQ1(V.w)

#define FMA4(acc,W,H) { acc=fmaf((W).x,(H).x,acc); acc=fmaf((W).y,(H).y,acc); \
                        acc=fmaf((W).z,(H).z,acc); acc=fmaf((W).w,(H).w,acc); }

// Butterfly (verified invariant: reg m holds value (m&3)^q2, half bit2(m)) +
// unified activation + cell update. Uses Q0..Q7, lolane, fs2, fs3, kae from scope.
#define TAIL8(CC, SA, SB, VA, VB, HN)                                                     \
    {                                                                                     \
        float r0=dppf<XOR1>(Q1), r1=dppf<XOR1>(Q0), r2=dppf<XOR1>(Q3), r3=dppf<XOR1>(Q2); \
        float r4=dppf<XOR1>(Q5), r5=dppf<XOR1>(Q4), r6=dppf<XOR1>(Q7), r7=dppf<XOR1>(Q6); \
        Q0+=r0; Q1+=r1; Q2+=r2; Q3+=r3; Q4+=r4; Q5+=r5; Q6+=r6; Q7+=r7;                   \
        float u0=dppf<XOR2>(Q2), u3=dppf<XOR2>(Q1), u4=dppf<XOR2>(Q6), u7=dppf<XOR2>(Q5); \
        Q0+=u0; Q3+=u3; Q4+=u4; Q7+=u7;                                                   \
        float m0=dppf<MIR7>(Q3), m4=dppf<MIR7>(Q7);                                       \
        Q0+=m0; Q4+=m4;                                                                   \
        const float yv = lolane ? Q0 : Q4;                                                \
        const float av = fmaf(fs2, __builtin_amdgcn_rcpf(1.f + __expf(kae*yv)), fs3);     \
        const float gi = dppf<BC0>(av);                                                   \
        const float gf = dppf<BC1>(av);                                                   \
        const float gg = dppf<BC2>(av);                                                   \
        const float go = dppf<BC3>(av);                                                   \
        const bool rst = lolane ? ((SA)==0) : ((SB)==0);                                  \
        const bool upd = lolane ? (VA) : (VB);                                            \
        const float igv = gi * gg;                                                        \
        const float ccn = rst ? igv : fmaf(gf, CC, igv);                                  \
        CC = upd ? ccn : CC;                                                              \
        HN = go * tanh_f(CC);                                                             \
    }

__device__ __forceinline__ float xsel4(float x0, float x1, float x2, float x3, int q2) {
    return (q2 & 2) ? ((q2 & 1) ? x3 : x2) : ((q2 & 1) ? x1 : x0);
}

// General (prologue) x-sourcing. Every outr read is row (w+s-8)&7 == (p-8)&7.
__device__ __forceinline__ float xload(const float* trajS, const float (*outr)[2],
                                       int w, int s, int q2) {
    float x0, x1, x2, x3;
    if (w == 0) {
        x0 = trajS[s*4+0]; x1 = trajS[s*4+1]; x2 = trajS[s*4+2]; x3 = trajS[s*4+3];
    } else if (w < 8) {
        if (s < 8 - w) {
            const int tt = w + s;
            x0 = trajS[tt*4+0]; x1 = trajS[tt*4+1]; x2 = trajS[tt*4+2]; x3 = trajS[tt*4+3];
        } else {
            const int tc = 2*w + s - 1;
            const int jo2 = (w + s - 8) & 7;
            x0 = trajS[tc*4+0]; x1 = trajS[tc*4+1];
            x2 = outr[jo2][0];  x3 = outr[jo2][1];
        }
    } else {
        const int tc = w + s;
        const int jo2 = (w + s) & 7;
        x0 = trajS[tc*4+0]; x1 = trajS[tc*4+1];
        x2 = outr[jo2][0];  x3 = outr[jo2][1];
    }
    return xsel4(x0, x1, x2, x3, q2);
}

// 2 blocks per row; row = bid&63, half = bid>>6 (pair r, r+64 same XCD heuristic).
// 1024 threads: pairSel = tid>>9 assigns each thread ONE pair (weights are
// slot-independent -> both halves hold identical weight registers). 16 waves ->
// 4/SIMD: per-wave chain halves, latency-hiding pool doubles, issue unchanged.
__global__ __launch_bounds__(1024, 4)
void or_lstm_coop(const float* __restrict__ traj,
                  const float* __restrict__ Wih0, const float* __restrict__ Whh0,
                  const float* __restrict__ bih0, const float* __restrict__ bhh0,
                  const float* __restrict__ Wih1, const float* __restrict__ Whh1,
                  const float* __restrict__ bih1, const float* __restrict__ bhh1,
                  const float* __restrict__ Wlin, const float* __restrict__ blin,
                  float* __restrict__ out, u64* __restrict__ ring)
{
    const int bid  = blockIdx.x;
    const int row  = bid & 63;
    const int half = bid >> 6;        // 0: slots 0-3, 1: slots 4-7  (pair r,r+64: same XCD)
    const int tid  = threadIdx.x;     // = ps*512 + j*8 + idx
    const int ps   = tid >> 9;        // pair select: waves 0-7 -> pair 0, waves 8-15 -> pair 1
    const int r5   = tid & 511;
    const int j    = r5 >> 3;
    const int idx  = r5 & 7;
    const int q2   = idx & 3;

    __shared__ __align__(16) float trajS[256 * 4];
    __shared__ __align__(16) float X0[2][4][64];   // [parity][local slot][j]
    __shared__ __align__(16) float X1[2][4][64];
    __shared__ float outr[8][2];                   // full ring, mirrored in both blocks

    if (tid < 256)
        ((f4*)trajS)[tid] = ((const f4*)(traj + (size_t)row * 256 * 4))[tid];
    if (tid < 512) { ((float*)X0)[tid] = 0.f; ((float*)X1)[tid] = 0.f; }

    // ---- gate-permuted weight slices (identical in both blocks AND both ps groups) ----
    const int jo = j * 64 + idx * 8;
    const int v0 = q2, v1 = 1 ^ q2, v2 = 2 ^ q2, v3 = 3 ^ q2;
    f4 W0a = *(const f4*)(Whh0 + v0*4096 + jo), W0b = *(const f4*)(Whh0 + v0*4096 + jo + 4);
    f4 W1a = *(const f4*)(Whh0 + v1*4096 + jo), W1b = *(const f4*)(Whh0 + v1*4096 + jo + 4);
    f4 W2a = *(const f4*)(Whh0 + v2*4096 + jo), W2b = *(const f4*)(Whh0 + v2*4096 + jo + 4);
    f4 W3a = *(const f4*)(Whh0 + v3*4096 + jo), W3b = *(const f4*)(Whh0 + v3*4096 + jo + 4);
    f4 U0a = *(const f4*)(Wih1 + v0*4096 + jo), U0b = *(const f4*)(Wih1 + v0*4096 + jo + 4);
    f4 U1a = *(const f4*)(Wih1 + v1*4096 + jo), U1b = *(const f4*)(Wih1 + v1*4096 + jo + 4);
    f4 U2a = *(const f4*)(Wih1 + v2*4096 + jo), U2b = *(const f4*)(Wih1 + v2*4096 + jo + 4);
    f4 U3a = *(const f4*)(Wih1 + v3*4096 + jo), U3b = *(const f4*)(Wih1 + v3*4096 + jo + 4);
    f4 V0a = *(const f4*)(Whh1 + v0*4096 + jo), V0b = *(const f4*)(Whh1 + v0*4096 + jo + 4);
    f4 V1a = *(const f4*)(Whh1 + v1*4096 + jo), V1b = *(const f4*)(Whh1 + v1*4096 + jo + 4);
    f4 V2a = *(const f4*)(Whh1 + v2*4096 + jo), V2b = *(const f4*)(Whh1 + v2*4096 + jo + 4);
    f4 V3a = *(const f4*)(Whh1 + v3*4096 + jo), V3b = *(const f4*)(Whh1 + v3*4096 + jo + 4);
    OPQ4(W0a) OPQ4(W0b) OPQ4(W1a) OPQ4(W1b) OPQ4(W2a) OPQ4(W2b) OPQ4(W3a) OPQ4(W3b)
    OPQ4(U0a) OPQ4(U0b) OPQ4(U1a) OPQ4(U1b) OPQ4(U2a) OPQ4(U2b) OPQ4(U3a) OPQ4(U3b)
    OPQ4(V0a) OPQ4(V0b) OPQ4(V1a) OPQ4(V1b) OPQ4(V2a) OPQ4(V2b) OPQ4(V3a) OPQ4(V3b)

    float wx0 = (idx < 4) ? Wih0[v0*256 + j*4 + q2] : 0.f;
    float wx1 = (idx < 4) ? Wih0[v1*256 + j*4 + q2] : 0.f;
    float wx2 = (idx < 4) ? Wih0[v2*256 + j*4 + q2] : 0.f;
    float wx3 = (idx < 4) ? Wih0[v3*256 + j*4 + q2] : 0.f;
    float bb00 = (idx == 0) ? (bih0[0*64+j] + bhh0[0*64+j]) : 0.f;
    float bb01 = (idx == 0) ? (bih0[1*64+j] + bhh0[1*64+j]) : 0.f;
    float bb02 = (idx == 0) ? (bih0[2*64+j] + bhh0[2*64+j]) : 0.f;
    float bb03 = (idx == 0) ? (bih0[3*64+j] + bhh0[3*64+j]) : 0.f;
    float bb10 = (idx == 0) ? (bih1[0*64+j] + bhh1[0*64+j]) : 0.f;
    float bb11 = (idx == 0) ? (bih1[1*64+j] + bhh1[1*64+j]) : 0.f;
    float bb12 = (idx == 0) ? (bih1[2*64+j] + bhh1[2*64+j]) : 0.f;
    float bb13 = (idx == 0) ? (bih1[3*64+j] + bhh1[3*64+j]) : 0.f;
    OPQ1(wx0) OPQ1(wx1) OPQ1(wx2) OPQ1(wx3)
    OPQ1(bb00) OPQ1(bb01) OPQ1(bb02) OPQ1(bb03)
    OPQ1(bb10) OPQ1(bb11) OPQ1(bb12) OPQ1(bb13)

    const float kae = (q2 == 2) ? -2.f : -1.f;
    const float fs2 = (q2 == 2) ?  2.f :  1.f;
    const float fs3 = (q2 == 2) ? -1.f :  0.f;

    // epilogue weights: wave 0 computes BOTH output components
    float wl0 = 0.f, wl1 = 0.f;
    if (tid < 64) { wl0 = Wlin[tid]; wl1 = Wlin[64 + tid]; }
    const float bl0 = blin[0], bl1 = blin[1];

    const bool lolane = (idx < 4);

    // this thread's pair: global slots cA,cB; local LDS slots lA,lB
    const int cA = 4*half + 2*ps, cB = cA + 1;
    const int lA = 2*ps,          lB = lA + 1;

    float cc0 = 0.f, cc1 = 0.f;    // own pair's cell state (A in quad0, B in quad1)

    __syncthreads();

    for (int p = 0; p < NPH2; ++p) {
        const int par = p & 1;
        const float* X0r = &X0[par ^ 1][0][idx * 8];
        const float* X1r = &X1[par ^ 1][0][idx * 8];
        float* X0w = &X0[par][0][j];
        float* X1w = &X1[par][0][j];

        const int gs = p & 7;                              // finishing global slot (p>=8)
        const bool prodBlk = (p >= 8) && ((gs >> 2) == half);

        const int sA0 = (p - cA) & 7,     sB0 = (p - cB) & 7;      // L0 steps
        const int sA1 = (p - 1 - cA) & 7, sB1 = (p - 1 - cB) & 7;  // L1 steps
        const bool vA1 = (unsigned)(p - 1 - sA1) < (unsigned)NW;
        const bool vB1 = (unsigned)(p - 1 - sB1) < (unsigned)NW;

        float QM[8];   // L0 bias + Whh0.h0 accumulators, live across barriers

        // ======== REGION A: L1(p-1) full + L0(p) h-part (OWN pair only) ========
        {
            const f4 ha = *(const f4*)(X0r + lA*64), hb = *(const f4*)(X0r + lA*64 + 4);
            const f4 hc = *(const f4*)(X0r + lB*64), hd = *(const f4*)(X0r + lB*64 + 4);

            {   // L0 main gates (bias + Whh0.h0; x added in region C)
                float qa0=bb00, qa1=bb01, qa2=bb02, qa3=bb03;
                float qb0=0.f,  qb1=0.f,  qb2=0.f,  qb3=0.f;
                float qa4=bb00, qa5=bb01, qa6=bb02, qa7=bb03;
                float qb4=0.f,  qb5=0.f,  qb6=0.f,  qb7=0.f;
                if (sA0 != 0) {
                    FMA4(qa0, W0a, ha) FMA4(qb0, W0b, hb)
                    FMA4(qa1, W1a, ha) FMA4(qb1, W1b, hb)
                    FMA4(qa2, W2a, ha) FMA4(qb2, W2b, hb)
                    FMA4(qa3, W3a, ha) FMA4(qb3, W3b, hb)
                }
                if (sB0 != 0) {
                    FMA4(qa4, W0a, hc) FMA4(qb4, W0b, hd)
                    FMA4(qa5, W1a, hc) FMA4(qb5, W1b, hd)
                    FMA4(qa6, W2a, hc) FMA4(qb6, W2b, hd)
                    FMA4(qa7, W3a, hc) FMA4(qb7, W3b, hd)
                }
                QM[0]=qa0+qb0; QM[1]=qa1+qb1; QM[2]=qa2+qb2; QM[3]=qa3+qb3;
                QM[4]=qa4+qb4; QM[5]=qa5+qb5; QM[6]=qa6+qb6; QM[7]=qa7+qb7;
            }

            {   // L1 gates: Wih1.h0(p-1) (reuse ha..hd) + Whh1.h1(p-2)
                float pa0=bb10, pa1=bb11, pa2=bb12, pa3=bb13;
                float pb0=0.f,  pb1=0.f,  pb2=0.f,  pb3=0.f;
                float pa4=bb10, pa5=bb11, pa6=bb12, pa7=bb13;
                float pb4=0.f,  pb5=0.f,  pb6=0.f,  pb7=0.f;
                FMA4(pa0, U0a, ha) FMA4(pb0, U0b, hb)
                FMA4(pa1, U1a, ha) FMA4(pb1, U1b, hb)
                FMA4(pa2, U2a, ha) FMA4(pb2, U2b, hb)
                FMA4(pa3, U3a, ha) FMA4(pb3, U3b, hb)
                FMA4(pa4, U0a, hc) FMA4(pb4, U0b, hd)
                FMA4(pa5, U1a, hc) FMA4(pb5, U1b, hd)
                FMA4(pa6, U2a, hc) FMA4(pb6, U2b, hd)
                FMA4(pa7, U3a, hc) FMA4(pb7, U3b, hd)
                if (sA1 != 0) {
                    const f4 ea = *(const f4*)(X1r + lA*64), eb = *(const f4*)(X1r + lA*64 + 4);
                    FMA4(pa0, V0a, ea) FMA4(pb0, V0b, eb)
                    FMA4(pa1, V1a, ea) FMA4(pb1, V1b, eb)
                    FMA4(pa2, V2a, ea) FMA4(pb2, V2b, eb)
                    FMA4(pa3, V3a, ea) FMA4(pb3, V3b, eb)
                }
                if (sB1 != 0) {
                    const f4 ec = *(const f4*)(X1r + lB*64), ed = *(const f4*)(X1r + lB*64 + 4);
                    FMA4(pa4, V0a, ec) FMA4(pb4, V0b, ed)
                    FMA4(pa5, V1a, ec) FMA4(pb5, V1b, ed)
                    FMA4(pa6, V2a, ec) FMA4(pb6, V2b, ed)
                    FMA4(pa7, V3a, ec) FMA4(pb7, V3b, ed)
                }
                float Q0 = pa0+pb0, Q1 = pa1+pb1, Q2 = pa2+pb2, Q3 = pa3+pb3;
                float Q4 = pa4+pb4, Q5 = pa5+pb5, Q6 = pa6+pb6, Q7 = pa7+pb7;
                float hn1;
                TAIL8(cc1, sA1, sB1, vA1, vB1, hn1)
                if (vA1 && idx == 0) X1w[lA*64] = hn1;
                if (vB1 && idx == 4) X1w[lB*64] = hn1;
            }
        }
        __syncthreads();                 // bar1: h1(p-1) visible (incl. finishing window p-8)

        // ======== REGION B: out[p-8] — produce (owner) / receive (single spinner) ========
        if (p >= 8) {
            const int w1 = p - 8;
            u64* rp = ring + ((size_t)row * 16 + (p & 15)) * 2;
            const unsigned tag = (unsigned)(p + 1);
            if (prodBlk) {
                // producer: wave 0 computes both Wlin dots from the finishing X1 slot
                if (tid < 64) {
                    const float hval = X1[par][gs & 3][tid];
                    float r0 = wl0 * hval, r1 = wl1 * hval;
                    #pragma unroll
                    for (int off = 32; off > 0; off >>= 1) {
                        r0 += __shfl_down(r0, off);
                        r1 += __shfl_down(r1, off);
                    }
                    if (tid == 0) {
                        const float prev0 = w1 ? outr[(w1-1) & 7][0] : trajS[7*4+2];
                        const float prev1 = w1 ? outr[(w1-1) & 7][1] : trajS[7*4+3];
                        const float o0 = prev0 + r0 + bl0;
                        const float o1 = prev1 + r1 + bl1;
                        outr[w1 & 7][0] = o0; outr[w1 & 7][1] = o1;
                        out[((size_t)row * NW + w1) * 2 + 0] = o0;
                        out[((size_t)row * NW + w1) * 2 + 1] = o1;
                        const u64 pk0 = ((u64)tag << 32) | (u64)__float_as_uint(o0);
                        const u64 pk1 = ((u64)tag << 32) | (u64)__float_as_uint(o1);
                        __hip_atomic_store(&rp[0], pk0, __ATOMIC_RELEASE, __HIP_MEMORY_SCOPE_AGENT);
                        __hip_atomic_store(&rp[1], pk1, __ATOMIC_RELEASE, __HIP_MEMORY_SCOPE_AGENT);
                    }
                }
            } else {
                // consumer: exactly ONE thread spins (ACQUIRE), fills the LDS ring
                if (tid == 0) {
                    u64 va, vb;
                    do { va = __hip_atomic_load(&rp[0], __ATOMIC_ACQUIRE, __HIP_MEMORY_SCOPE_AGENT);
                    } while ((unsigned)(va >> 32) != tag);
                    do { vb = __hip_atomic_load(&rp[1], __ATOMIC_ACQUIRE, __HIP_MEMORY_SCOPE_AGENT);
                    } while ((unsigned)(vb >> 32) != tag);
                    outr[w1 & 7][0] = __uint_as_float((unsigned)va);
                    outr[w1 & 7][1] = __uint_as_float((unsigned)vb);
                }
            }
        }
        __syncthreads();                 // bar2: outr[(p-8)&7] visible

        // ======== REGION C: rank-2 x-feedback + L0 TAIL (OWN pair only) ========
        float xA, xB;
        if (p >= 15) {
            const float xc = xsel4(trajS[p*4+0], trajS[p*4+1],
                                   outr[p & 7][0], outr[p & 7][1], q2);
            xA = xc; xB = xc;
        } else {
            const int wA = p - sA0, wB = p - sB0;
            xA = ((unsigned)wA < (unsigned)NW) ? xload(trajS, outr, wA, sA0, q2) : 0.f;
            xB = ((unsigned)wB < (unsigned)NW) ? xload(trajS, outr, wB, sB0, q2) : 0.f;
        }
        {
            const bool vA0 = (unsigned)(p - sA0) < (unsigned)NW;
            const bool vB0 = (unsigned)(p - sB0) < (unsigned)NW;
            float Q0 = fmaf(wx0, xA, QM[0]);
            float Q1 = fmaf(wx1, xA, QM[1]);
            float Q2 = fmaf(wx2, xA, QM[2]);
            float Q3 = fmaf(wx3, xA, QM[3]);
            float Q4 = fmaf(wx0, xB, QM[4]);
            float Q5 = fmaf(wx1, xB, QM[5]);
            float Q6 = fmaf(wx2, xB, QM[6]);
            float Q7 = fmaf(wx3, xB, QM[7]);
            float hn0;
            TAIL8(cc0, sA0, sB0, vA0, vB0, hn0)
            if (vA0 && idx == 0) X0w[lA*64] = hn0;
            if (vB0 && idx == 4) X0w[lB*64] = hn0;
        }
        __syncthreads();                 // bar3: h0(p) visible for next phase
    }

    // ---- final hidden/cell state: window NW-1 = global slot 7 -> half 1, pair 1, B-side ----
    // h0 final written phase 254 (par 0); h1 final phase 255 (par 1). B-side -> hi quad (idx==4).
    if (half == 1 && ps == 1 && idx == 4) {
        float* hn = out + (size_t)NB * NW * 2;
        float* cn = hn + 2 * NB * 64;
        hn[(0 * NB + row) * 64 + j] = X0[0][3][j];
        hn[(1 * NB + row) * 64 + j] = X1[1][3][j];
        cn[(0 * NB + row) * 64 + j] = cc0;
        cn[(1 * NB + row) * 64 + j] = cc1;
    }
}

extern "C" void kernel_launch(void* const* d_in, const int* in_sizes, int n_in,
                              void* d_out, int out_size, void* d_ws, size_t ws_size,
                              hipStream_t stream) {
    const float* traj = (const float*)d_in[0];
    const float* Wih0 = (const float*)d_in[1];
    const float* Whh0 = (const float*)d_in[2];
    const float* bih0 = (const float*)d_in[3];
    const float* bhh0 = (const float*)d_in[4];
    const float* Wih1 = (const float*)d_in[5];
    const float* Whh1 = (const float*)d_in[6];
    const float* bih1 = (const float*)d_in[7];
    const float* bhh1 = (const float*)d_in[8];
    const float* Wlin = (const float*)d_in[9];
    const float* blin = (const float*)d_in[10];
    float* out = (float*)d_out;

    // workspace: ring = u64[64 rows][16 slots][2] (16 KB), tag-embedded values.
    u64* ring = (u64*)d_ws;
    // zero tags every launch (graph-captured -> re-runs on every replay); first tag used is 9.
    hipMemsetAsync(d_ws, 0, (size_t)NB * 16 * 2 * sizeof(u64), stream);

    void* kargs[] = { (void*)&traj, (void*)&Wih0, (void*)&Whh0, (void*)&bih0, (void*)&bhh0,
                      (void*)&Wih1, (void*)&Whh1, (void*)&bih1, (void*)&bhh1,
                      (void*)&Wlin, (void*)&blin, (void*)&out, (void*)&ring };
    hipLaunchCooperativeKernel((const void*)or_lstm_coop, dim3(NB * 2), dim3(1024),
                               kargs, 0, stream);
}

// Round 17
// 987.949 us; speedup vs baseline: 4.4335x; 4.4335x over previous
//
#include <hip/hip_runtime.h>
#include <math.h>

typedef float4 f4;
typedef unsigned long long u64;
#define NW 248
#define NB 64
#define NPH2 (NW + 8)   // 256 phases; phase p: L0 step p, L1 step p-1 (window-parallel, split 2 blocks/row)

// ============================================================================
// FINAL CHAMPION (round 9/15 structure, 912us core; session 1984 -> 912, 2.18x).
// Decomposition: 248 overlapping windows run 8-at-a-time, staggered 1 step/phase;
// each row split across 2 blocks (4 slots each); the only cross-block coupling is
// out[p-8] (2 floats/phase) via tagged-u64 ring in workspace.
// Complete failure catalog (all measured; do NOT retry):
//  - r8:  >1 spinner thread/block on agent atomics -> coherent-poll storm (16x).
//  - r10: 4 blocks/row -> exchange exposure doubles, 1692us.
//  - r11: RELAXED atomic spin-loads lower to per-poll writes (WRITE_SIZE 15MB, +24%).
//  - r11/r12: duplicated region-A code paths -> VGPR 128 + scratch spill (+40%).
//  - r13: producer-only bar1 / post-after-store reorder: neutral-negative (945).
//  - r14/r16: 1024thr (pair-split, 4 waves/SIMD): BOTH occupancy knobs
//    (amdgpu_waves_per_eu(4,4) and __launch_bounds__(1024,4)) rejected ->
//    allocator provisions 64 VGPR -> total spill (315MB FETCH, 4350us).
//    Weight-resident design is locked to 512 threads / 2 waves per SIMD.
// Structural floor: ~8.6K cyc/phase = ~3.9K issue (VALU ~46% of active CUs)
// + 3 barriers + 1 L2 exchange + 2-wave chain latency. Not a HW roofline
// (HBM 0.06%, VALU 46%) — a floor of this decomposition's neighborhood.
// ============================================================================

__device__ __forceinline__ float tanh_f(float x) { return 2.0f * __builtin_amdgcn_rcpf(1.0f + __expf(-2.0f * x)) - 1.0f; }

template<int CTRL>
__device__ __forceinline__ float dppf(float v) {
    return __int_as_float(__builtin_amdgcn_update_dpp(0, __float_as_int(v), CTRL, 0xF, 0xF, true));
}
#define XOR1 0xB1   // quad_perm [1,0,3,2]
#define XOR2 0x4E   // quad_perm [2,3,0,1]
#define MIR7 0x141  // ROW_HALF_MIRROR: lane i -> 7-i within 8 (== xor 7)
#define BC0  0x00
#define BC1  0x55
#define BC2  0xAA
#define BC3  0xFF

#define OPQ1(X) asm volatile("" : "+v"(X));
#define OPQ4(V) OPQ1(V.x) OPQ1(V.y) OPQ1(V.z) OPQ1(V.w)

#define FMA4(acc,W,H) { acc=fmaf((W).x,(H).x,acc); acc=fmaf((W).y,(H).y,acc); \
                        acc=fmaf((W).z,(H).z,acc); acc=fmaf((W).w,(H).w,acc); }

// Butterfly (verified invariant: reg m holds value (m&3)^q2, half bit2(m)) +
// unified activation + cell update. Uses Q0..Q7, lolane, fs2, fs3, kae from scope.
#define TAIL8(CC, SA, SB, VA, VB, HN)                                                     \
    {                                                                                     \
        float r0=dppf<XOR1>(Q1), r1=dppf<XOR1>(Q0), r2=dppf<XOR1>(Q3), r3=dppf<XOR1>(Q2); \
        float r4=dppf<XOR1>(Q5), r5=dppf<XOR1>(Q4), r6=dppf<XOR1>(Q7), r7=dppf<XOR1>(Q6); \
        Q0+=r0; Q1+=r1; Q2+=r2; Q3+=r3; Q4+=r4; Q5+=r5; Q6+=r6; Q7+=r7;                   \
        float u0=dppf<XOR2>(Q2), u3=dppf<XOR2>(Q1), u4=dppf<XOR2>(Q6), u7=dppf<XOR2>(Q5); \
        Q0+=u0; Q3+=u3; Q4+=u4; Q7+=u7;                                                   \
        float m0=dppf<MIR7>(Q3), m4=dppf<MIR7>(Q7);                                       \
        Q0+=m0; Q4+=m4;                                                                   \
        const float yv = lolane ? Q0 : Q4;                                                \
        const float av = fmaf(fs2, __builtin_amdgcn_rcpf(1.f + __expf(kae*yv)), fs3);     \
        const float gi = dppf<BC0>(av);                                                   \
        const float gf = dppf<BC1>(av);                                                   \
        const float gg = dppf<BC2>(av);                                                   \
        const float go = dppf<BC3>(av);                                                   \
        const bool rst = lolane ? ((SA)==0) : ((SB)==0);                                  \
        const bool upd = lolane ? (VA) : (VB);                                            \
        const float igv = gi * gg;                                                        \
        const float ccn = rst ? igv : fmaf(gf, CC, igv);                                  \
        CC = upd ? ccn : CC;                                                              \
        HN = go * tanh_f(CC);                                                             \
    }

__device__ __forceinline__ float xsel4(float x0, float x1, float x2, float x3, int q2) {
    return (q2 & 2) ? ((q2 & 1) ? x3 : x2) : ((q2 & 1) ? x1 : x0);
}

// General (prologue) x-sourcing. Every outr read is row (w+s-8)&7 == (p-8)&7.
__device__ __forceinline__ float xload(const float* trajS, const float (*outr)[2],
                                       int w, int s, int q2) {
    float x0, x1, x2, x3;
    if (w == 0) {
        x0 = trajS[s*4+0]; x1 = trajS[s*4+1]; x2 = trajS[s*4+2]; x3 = trajS[s*4+3];
    } else if (w < 8) {
        if (s < 8 - w) {
            const int tt = w + s;
            x0 = trajS[tt*4+0]; x1 = trajS[tt*4+1]; x2 = trajS[tt*4+2]; x3 = trajS[tt*4+3];
        } else {
            const int tc = 2*w + s - 1;
            const int jo2 = (w + s - 8) & 7;
            x0 = trajS[tc*4+0]; x1 = trajS[tc*4+1];
            x2 = outr[jo2][0];  x3 = outr[jo2][1];
        }
    } else {
        const int tc = w + s;
        const int jo2 = (w + s) & 7;
        x0 = trajS[tc*4+0]; x1 = trajS[tc*4+1];
        x2 = outr[jo2][0];  x3 = outr[jo2][1];
    }
    return xsel4(x0, x1, x2, x3, q2);
}

// 2 blocks per row. SAME-XCD PAIRING: row = bid&63, half = bid>>6 -> the pair is
// bids {r, r+64}, both == r (mod 8) -> same XCD under round-robin dispatch, so the
// exchange round trip stays in one L2 (perf heuristic only; correctness unaffected).
// Exchange = out[p-8] as TWO tagged u64 atomics {tag=p+1, f32}; exactly ONE spinner
// thread per block.
__global__ __launch_bounds__(512) __attribute__((amdgpu_waves_per_eu(2, 2)))
void or_lstm_coop(const float* __restrict__ traj,
                  const float* __restrict__ Wih0, const float* __restrict__ Whh0,
                  const float* __restrict__ bih0, const float* __restrict__ bhh0,
                  const float* __restrict__ Wih1, const float* __restrict__ Whh1,
                  const float* __restrict__ bih1, const float* __restrict__ bhh1,
                  const float* __restrict__ Wlin, const float* __restrict__ blin,
                  float* __restrict__ out, u64* __restrict__ ring)
{
    const int bid  = blockIdx.x;
    const int row  = bid & 63;
    const int half = bid >> 6;        // 0: slots 0-3, 1: slots 4-7  (pair on same XCD)
    const int tid  = threadIdx.x;     // = j*8 + idx
    const int j    = tid >> 3;
    const int idx  = tid & 7;
    const int q2   = idx & 3;

    __shared__ __align__(16) float trajS[256 * 4];
    __shared__ __align__(16) float X0[2][4][64];   // [parity][local slot][j]
    __shared__ __align__(16) float X1[2][4][64];
    __shared__ float outr[8][2];                   // full ring, mirrored in both blocks

    if (tid < 256)
        ((f4*)trajS)[tid] = ((const f4*)(traj + (size_t)row * 256 * 4))[tid];
    ((float*)X0)[tid] = 0.f;                       // 2*4*64 = 512 floats each
    ((float*)X1)[tid] = 0.f;

    // ---- gate-permuted weight slices (identical in both blocks; shared across slots) ----
    const int jo = j * 64 + idx * 8;
    const int v0 = q2, v1 = 1 ^ q2, v2 = 2 ^ q2, v3 = 3 ^ q2;
    f4 W0a = *(const f4*)(Whh0 + v0*4096 + jo), W0b = *(const f4*)(Whh0 + v0*4096 + jo + 4);
    f4 W1a = *(const f4*)(Whh0 + v1*4096 + jo), W1b = *(const f4*)(Whh0 + v1*4096 + jo + 4);
    f4 W2a = *(const f4*)(Whh0 + v2*4096 + jo), W2b = *(const f4*)(Whh0 + v2*4096 + jo + 4);
    f4 W3a = *(const f4*)(Whh0 + v3*4096 + jo), W3b = *(const f4*)(Whh0 + v3*4096 + jo + 4);
    f4 U0a = *(const f4*)(Wih1 + v0*4096 + jo), U0b = *(const f4*)(Wih1 + v0*4096 + jo + 4);
    f4 U1a = *(const f4*)(Wih1 + v1*4096 + jo), U1b = *(const f4*)(Wih1 + v1*4096 + jo + 4);
    f4 U2a = *(const f4*)(Wih1 + v2*4096 + jo), U2b = *(const f4*)(Wih1 + v2*4096 + jo + 4);
    f4 U3a = *(const f4*)(Wih1 + v3*4096 + jo), U3b = *(const f4*)(Wih1 + v3*4096 + jo + 4);
    f4 V0a = *(const f4*)(Whh1 + v0*4096 + jo), V0b = *(const f4*)(Whh1 + v0*4096 + jo + 4);
    f4 V1a = *(const f4*)(Whh1 + v1*4096 + jo), V1b = *(const f4*)(Whh1 + v1*4096 + jo + 4);
    f4 V2a = *(const f4*)(Whh1 + v2*4096 + jo), V2b = *(const f4*)(Whh1 + v2*4096 + jo + 4);
    f4 V3a = *(const f4*)(Whh1 + v3*4096 + jo), V3b = *(const f4*)(Whh1 + v3*4096 + jo + 4);
    OPQ4(W0a) OPQ4(W0b) OPQ4(W1a) OPQ4(W1b) OPQ4(W2a) OPQ4(W2b) OPQ4(W3a) OPQ4(W3b)
    OPQ4(U0a) OPQ4(U0b) OPQ4(U1a) OPQ4(U1b) OPQ4(U2a) OPQ4(U2b) OPQ4(U3a) OPQ4(U3b)
    OPQ4(V0a) OPQ4(V0b) OPQ4(V1a) OPQ4(V1b) OPQ4(V2a) OPQ4(V2b) OPQ4(V3a) OPQ4(V3b)

    float wx0 = (idx < 4) ? Wih0[v0*256 + j*4 + q2] : 0.f;
    float wx1 = (idx < 4) ? Wih0[v1*256 + j*4 + q2] : 0.f;
    float wx2 = (idx < 4) ? Wih0[v2*256 + j*4 + q2] : 0.f;
    float wx3 = (idx < 4) ? Wih0[v3*256 + j*4 + q2] : 0.f;
    float bb00 = (idx == 0) ? (bih0[0*64+j] + bhh0[0*64+j]) : 0.f;
    float bb01 = (idx == 0) ? (bih0[1*64+j] + bhh0[1*64+j]) : 0.f;
    float bb02 = (idx == 0) ? (bih0[2*64+j] + bhh0[2*64+j]) : 0.f;
    float bb03 = (idx == 0) ? (bih0[3*64+j] + bhh0[3*64+j]) : 0.f;
    float bb10 = (idx == 0) ? (bih1[0*64+j] + bhh1[0*64+j]) : 0.f;
    float bb11 = (idx == 0) ? (bih1[1*64+j] + bhh1[1*64+j]) : 0.f;
    float bb12 = (idx == 0) ? (bih1[2*64+j] + bhh1[2*64+j]) : 0.f;
    float bb13 = (idx == 0) ? (bih1[3*64+j] + bhh1[3*64+j]) : 0.f;
    OPQ1(wx0) OPQ1(wx1) OPQ1(wx2) OPQ1(wx3)
    OPQ1(bb00) OPQ1(bb01) OPQ1(bb02) OPQ1(bb03)
    OPQ1(bb10) OPQ1(bb11) OPQ1(bb12) OPQ1(bb13)

    const float kae = (q2 == 2) ? -2.f : -1.f;
    const float fs2 = (q2 == 2) ?  2.f :  1.f;
    const float fs3 = (q2 == 2) ? -1.f :  0.f;

    // epilogue weights: wave 0 computes BOTH output components
    float wl0 = 0.f, wl1 = 0.f;
    if (tid < 64) { wl0 = Wlin[tid]; wl1 = Wlin[64 + tid]; }
    const float bl0 = blin[0], bl1 = blin[1];

    const bool lolane = (idx < 4);
    float cc0[2] = {0.f, 0.f};    // L0 cell per local pair (A in quad0, B in quad1)
    float cc1[2] = {0.f, 0.f};

    __syncthreads();

    for (int p = 0; p < NPH2; ++p) {
        const int par = p & 1;
        const float* X0r = &X0[par ^ 1][0][idx * 8];
        const float* X1r = &X1[par ^ 1][0][idx * 8];
        float* X0w = &X0[par][0][j];
        float* X1w = &X1[par][0][j];

        float QM[2][8];   // L0 bias + Whh0.h0 accumulators, live across barriers

        // ======== REGION A: L1(p-1) full + L0(p) h-part, own 2 pairs ========
        #pragma unroll
        for (int P = 0; P < 2; ++P) {
            const int cA = 4*half + 2*P, cB = cA + 1;    // global slots
            const int lA = 2*P,          lB = lA + 1;    // local slots
            const int sA0 = (p - cA) & 7,     sB0 = (p - cB) & 7;
            const int sA1 = (p - 1 - cA) & 7, sB1 = (p - 1 - cB) & 7;
            const bool vA1 = (unsigned)(p - 1 - sA1) < (unsigned)NW;
            const bool vB1 = (unsigned)(p - 1 - sB1) < (unsigned)NW;

            const f4 ha = *(const f4*)(X0r + lA*64), hb = *(const f4*)(X0r + lA*64 + 4);
            const f4 hc = *(const f4*)(X0r + lB*64), hd = *(const f4*)(X0r + lB*64 + 4);

            {   // L0 main gates (bias + Whh0.h0; x added in region C)
                float qa0=bb00, qa1=bb01, qa2=bb02, qa3=bb03;
                float qb0=0.f,  qb1=0.f,  qb2=0.f,  qb3=0.f;
                float qa4=bb00, qa5=bb01, qa6=bb02, qa7=bb03;
                float qb4=0.f,  qb5=0.f,  qb6=0.f,  qb7=0.f;
                if (sA0 != 0) {
                    FMA4(qa0, W0a, ha) FMA4(qb0, W0b, hb)
                    FMA4(qa1, W1a, ha) FMA4(qb1, W1b, hb)
                    FMA4(qa2, W2a, ha) FMA4(qb2, W2b, hb)
                    FMA4(qa3, W3a, ha) FMA4(qb3, W3b, hb)
                }
                if (sB0 != 0) {
                    FMA4(qa4, W0a, hc) FMA4(qb4, W0b, hd)
                    FMA4(qa5, W1a, hc) FMA4(qb5, W1b, hd)
                    FMA4(qa6, W2a, hc) FMA4(qb6, W2b, hd)
                    FMA4(qa7, W3a, hc) FMA4(qb7, W3b, hd)
                }
                QM[P][0]=qa0+qb0; QM[P][1]=qa1+qb1; QM[P][2]=qa2+qb2; QM[P][3]=qa3+qb3;
                QM[P][4]=qa4+qb4; QM[P][5]=qa5+qb5; QM[P][6]=qa6+qb6; QM[P][7]=qa7+qb7;
            }

            {   // L1 gates: Wih1.h0(p-1) (reuse ha..hd) + Whh1.h1(p-2)
                float pa0=bb10, pa1=bb11, pa2=bb12, pa3=bb13;
                float pb0=0.f,  pb1=0.f,  pb2=0.f,  pb3=0.f;
                float pa4=bb10, pa5=bb11, pa6=bb12, pa7=bb13;
                float pb4=0.f,  pb5=0.f,  pb6=0.f,  pb7=0.f;
                FMA4(pa0, U0a, ha) FMA4(pb0, U0b, hb)
                FMA4(pa1, U1a, ha) FMA4(pb1, U1b, hb)
                FMA4(pa2, U2a, ha) FMA4(pb2, U2b, hb)
                FMA4(pa3, U3a, ha) FMA4(pb3, U3b, hb)
                FMA4(pa4, U0a, hc) FMA4(pb4, U0b, hd)
                FMA4(pa5, U1a, hc) FMA4(pb5, U1b, hd)
                FMA4(pa6, U2a, hc) FMA4(pb6, U2b, hd)
                FMA4(pa7, U3a, hc) FMA4(pb7, U3b, hd)
                if (sA1 != 0) {
                    const f4 ea = *(const f4*)(X1r + lA*64), eb = *(const f4*)(X1r + lA*64 + 4);
                    FMA4(pa0, V0a, ea) FMA4(pb0, V0b, eb)
                    FMA4(pa1, V1a, ea) FMA4(pb1, V1b, eb)
                    FMA4(pa2, V2a, ea) FMA4(pb2, V2b, eb)
                    FMA4(pa3, V3a, ea) FMA4(pb3, V3b, eb)
                }
                if (sB1 != 0) {
                    const f4 ec = *(const f4*)(X1r + lB*64), ed = *(const f4*)(X1r + lB*64 + 4);
                    FMA4(pa4, V0a, ec) FMA4(pb4, V0b, ed)
                    FMA4(pa5, V1a, ec) FMA4(pb5, V1b, ed)
                    FMA4(pa6, V2a, ec) FMA4(pb6, V2b, ed)
                    FMA4(pa7, V3a, ec) FMA4(pb7, V3b, ed)
                }
                float Q0 = pa0+pb0, Q1 = pa1+pb1, Q2 = pa2+pb2, Q3 = pa3+pb3;
                float Q4 = pa4+pb4, Q5 = pa5+pb5, Q6 = pa6+pb6, Q7 = pa7+pb7;
                float hn1;
                TAIL8(cc1[P], sA1, sB1, vA1, vB1, hn1)
                if (vA1 && idx == 0) X1w[lA*64] = hn1;
                if (vB1 && idx == 4) X1w[lB*64] = hn1;
            }
        }
        __syncthreads();                 // bar1: h1(p-1) visible (incl. finishing window p-8)

        // ======== REGION B: out[p-8] — produce (owner) / receive (single spinner) ========
        if (p >= 8) {
            const int w1 = p - 8;
            const int gs = p & 7;                                  // finishing global slot
            u64* rp = ring + ((size_t)row * 16 + (p & 15)) * 2;
            const unsigned tag = (unsigned)(p + 1);
            if ((gs >> 2) == half) {
                // producer: wave 0 computes both Wlin dots from own X1 slot
                if (tid < 64) {
                    const float hval = X1[par][gs & 3][tid];
                    float r0 = wl0 * hval, r1 = wl1 * hval;
                    #pragma unroll
                    for (int off = 32; off > 0; off >>= 1) {
                        r0 += __shfl_down(r0, off);
                        r1 += __shfl_down(r1, off);
                    }
                    if (tid == 0) {
                        const float prev0 = w1 ? outr[(w1-1) & 7][0] : trajS[7*4+2];
                        const float prev1 = w1 ? outr[(w1-1) & 7][1] : trajS[7*4+3];
                        const float o0 = prev0 + r0 + bl0;
                        const float o1 = prev1 + r1 + bl1;
                        outr[w1 & 7][0] = o0; outr[w1 & 7][1] = o1;
                        out[((size_t)row * NW + w1) * 2 + 0] = o0;
                        out[((size_t)row * NW + w1) * 2 + 1] = o1;
                        const u64 pk0 = ((u64)tag << 32) | (u64)__float_as_uint(o0);
                        const u64 pk1 = ((u64)tag << 32) | (u64)__float_as_uint(o1);
                        __hip_atomic_store(&rp[0], pk0, __ATOMIC_RELEASE, __HIP_MEMORY_SCOPE_AGENT);
                        __hip_atomic_store(&rp[1], pk1, __ATOMIC_RELEASE, __HIP_MEMORY_SCOPE_AGENT);
                    }
                }
            } else {
                // consumer: exactly ONE thread spins, fills the LDS ring
                if (tid == 0) {
                    u64 va, vb;
                    do { va = __hip_atomic_load(&rp[0], __ATOMIC_ACQUIRE, __HIP_MEMORY_SCOPE_AGENT);
                    } while ((unsigned)(va >> 32) != tag);
                    do { vb = __hip_atomic_load(&rp[1], __ATOMIC_ACQUIRE, __HIP_MEMORY_SCOPE_AGENT);
                    } while ((unsigned)(vb >> 32) != tag);
                    outr[w1 & 7][0] = __uint_as_float((unsigned)va);
                    outr[w1 & 7][1] = __uint_as_float((unsigned)vb);
                }
            }
        }
        __syncthreads();                 // bar2: outr[(p-8)&7] visible

        // ======== REGION C: rank-2 x-feedback + L0 TAILs ========
        float xs0, xs1, xs2, xs3;
        if (p >= 15) {
            const float xc = xsel4(trajS[p*4+0], trajS[p*4+1],
                                   outr[p & 7][0], outr[p & 7][1], q2);
            xs0 = xs1 = xs2 = xs3 = xc;
        } else {
            float t[4];
            #pragma unroll
            for (int c = 0; c < 4; ++c) {
                const int g = 4*half + c;
                const int s = (p - g) & 7;
                const int w = p - s;
                t[c] = ((unsigned)w < (unsigned)NW) ? xload(trajS, outr, w, s, q2) : 0.f;
            }
            xs0 = t[0]; xs1 = t[1]; xs2 = t[2]; xs3 = t[3];
        }
        #pragma unroll
        for (int P = 0; P < 2; ++P) {
            const int cA = 4*half + 2*P, cB = cA + 1;
            const int lA = 2*P,          lB = lA + 1;
            const int sA0 = (p - cA) & 7, sB0 = (p - cB) & 7;
            const bool vA0 = (unsigned)(p - sA0) < (unsigned)NW;
            const bool vB0 = (unsigned)(p - sB0) < (unsigned)NW;
            const float xA = P ? xs2 : xs0;
            const float xB = P ? xs3 : xs1;
            float Q0 = fmaf(wx0, xA, QM[P][0]);
            float Q1 = fmaf(wx1, xA, QM[P][1]);
            float Q2 = fmaf(wx2, xA, QM[P][2]);
            float Q3 = fmaf(wx3, xA, QM[P][3]);
            float Q4 = fmaf(wx0, xB, QM[P][4]);
            float Q5 = fmaf(wx1, xB, QM[P][5]);
            float Q6 = fmaf(wx2, xB, QM[P][6]);
            float Q7 = fmaf(wx3, xB, QM[P][7]);
            float hn0;
            TAIL8(cc0[P], sA0, sB0, vA0, vB0, hn0)
            if (vA0 && idx == 0) X0w[lA*64] = hn0;
            if (vB0 && idx == 4) X0w[lB*64] = hn0;
        }
        __syncthreads();                 // bar3: h0(p) visible for next phase
    }

    // ---- final hidden/cell state: window NW-1 = global slot 7 -> half 1, local slot 3 ----
    // h0 final written phase 254 (par 0); h1 final phase 255 (par 1). Pair P=1, B-side -> hi quad.
    if (half == 1 && idx == 4) {
        float* hn = out + (size_t)NB * NW * 2;
        float* cn = hn + 2 * NB * 64;
        hn[(0 * NB + row) * 64 + j] = X0[0][3][j];
        hn[(1 * NB + row) * 64 + j] = X1[1][3][j];
        cn[(0 * NB + row) * 64 + j] = cc0[1];
        cn[(1 * NB + row) * 64 + j] = cc1[1];
    }
}

extern "C" void kernel_launch(void* const* d_in, const int* in_sizes, int n_in,
                              void* d_out, int out_size, void* d_ws, size_t ws_size,
                              hipStream_t stream) {
    const float* traj = (const float*)d_in[0];
    const float* Wih0 = (const float*)d_in[1];
    const float* Whh0 = (const float*)d_in[2];
    const float* bih0 = (const float*)d_in[3];
    const float* bhh0 = (const float*)d_in[4];
    const float* Wih1 = (const float*)d_in[5];
    const float* Whh1 = (const float*)d_in[6];
    const float* bih1 = (const float*)d_in[7];
    const float* bhh1 = (const float*)d_in[8];
    const float* Wlin = (const float*)d_in[9];
    const float* blin = (const float*)d_in[10];
    float* out = (float*)d_out;

    // workspace: ring = u64[64 rows][16 slots][2] (16 KB), tag-embedded values.
    u64* ring = (u64*)d_ws;
    // zero tags every launch (graph-captured -> re-runs on every replay); first tag used is 9.
    hipMemsetAsync(d_ws, 0, (size_t)NB * 16 * 2 * sizeof(u64), stream);

    void* kargs[] = { (void*)&traj, (void*)&Wih0, (void*)&Whh0, (void*)&bih0, (void*)&bhh0,
                      (void*)&Wih1, (void*)&Whh1, (void*)&bih1, (void*)&bhh1,
                      (void*)&Wlin, (void*)&blin, (void*)&out, (void*)&ring };
    hipLaunchCooperativeKernel((const void*)or_lstm_coop, dim3(NB * 2), dim3(512),
                               kargs, 0, stream);
}

// Round 18
// 955.830 us; speedup vs baseline: 4.5825x; 1.0336x over previous
//
#include <hip/hip_runtime.h>
#include <math.h>

typedef float4 f4;
typedef unsigned long long u64;
typedef __attribute__((ext_vector_type(2))) float v2f;
typedef __attribute__((ext_vector_type(4))) float v4f;
#define NW 248
#define NB 64
#define NPH2 (NW + 8)   // 256 phases; phase p: L0 step p, L1 step p-1 (window-parallel, split 2 blocks/row)

// ============================================================================
// Champion (r9/r15, 912us) + ONE change: packed-FP32 dot products.
// MI355X vector FP32 peak (157.3 TF) requires v_pk_fma_f32 (VOP3P, 2 FMA/inst);
// scalar v_fma_f32 runs at half rate. __builtin_elementwise_fma on <2 x float>
// lowers to v_pk_fma_f32 on gfx90a+. 192 packed insts replace 384 scalar
// (~770 cyc/SIMD/phase issue saved). Accumulator float-count unchanged (8 v2
// per pair-layer = 16 floats); weights laundered as 48 even-aligned v2 pairs.
// Session failure catalog (all measured; do NOT retry):
//  - r8:  >1 spinner thread/block on agent atomics -> coherent-poll storm (16x).
//  - r10: 4 blocks/row -> exchange exposure doubles, 1692us.
//  - r11: RELAXED atomic spin-loads lower to per-poll writes (WRITE_SIZE 15MB).
//  - r11/r12: duplicated region-A code paths -> VGPR 128 + scratch spill.
//  - r13: producer-only bar1 / post reorder: neutral-negative.
//  - r14/r16: 1024thr: both occupancy knobs rejected -> 64-VGPR provision, spill.
// Health checks: VGPR 104-120 + WRITE ~1.5KB = OK; VGPR >128 or WRITE in MBs =
// RA marshalling/spill -> revert to r15 champion.
// ============================================================================

__device__ __forceinline__ float tanh_f(float x) { return 2.0f * __builtin_amdgcn_rcpf(1.0f + __expf(-2.0f * x)) - 1.0f; }

template<int CTRL>
__device__ __forceinline__ float dppf(float v) {
    return __int_as_float(__builtin_amdgcn_update_dpp(0, __float_as_int(v), CTRL, 0xF, 0xF, true));
}
#define XOR1 0xB1   // quad_perm [1,0,3,2]
#define XOR2 0x4E   // quad_perm [2,3,0,1]
#define MIR7 0x141  // ROW_HALF_MIRROR: lane i -> 7-i within 8 (== xor 7)
#define BC0  0x00
#define BC1  0x55
#define BC2  0xAA
#define BC3  0xFF

#define OPQ1(X) asm volatile("" : "+v"(X));

// packed fp32 fma: acc.x += W.x*H.x; acc.y += W.y*H.y  (v_pk_fma_f32)
#define PFMA(acc,W,H) (acc) = __builtin_elementwise_fma((W), (H), (acc));
// 8-float dot contribution of weight group N (4 v2 slices) vs h slices h0..h3
#define DOTG(N,h0,h1,h2,h3,ACC) \
  PFMA(ACC, N##0, h0) PFMA(ACC, N##1, h1) PFMA(ACC, N##2, h2) PFMA(ACC, N##3, h3)

#define LO2(V) __builtin_shufflevector((V), (V), 0, 1)
#define HI2(V) __builtin_shufflevector((V), (V), 2, 3)

// per-gate weight slice as 4 v2 (8 floats), even-aligned pairs for VOP3P
#define LDW2(N, SRC, G) \
  v2f N##0 = *(const v2f*)((SRC) + (G)*4096 + jo),     \
      N##1 = *(const v2f*)((SRC) + (G)*4096 + jo + 2), \
      N##2 = *(const v2f*)((SRC) + (G)*4096 + jo + 4), \
      N##3 = *(const v2f*)((SRC) + (G)*4096 + jo + 6);
#define OPQW(N) OPQ1(N##0) OPQ1(N##1) OPQ1(N##2) OPQ1(N##3)

// Butterfly (verified invariant: reg m holds value (m&3)^q2, half bit2(m)) +
// unified activation + cell update. Uses Q0..Q7, lolane, fs2, fs3, kae from scope.
#define TAIL8(CC, SA, SB, VA, VB, HN)                                                     \
    {                                                                                     \
        float r0=dppf<XOR1>(Q1), r1=dppf<XOR1>(Q0), r2=dppf<XOR1>(Q3), r3=dppf<XOR1>(Q2); \
        float r4=dppf<XOR1>(Q5), r5=dppf<XOR1>(Q4), r6=dppf<XOR1>(Q7), r7=dppf<XOR1>(Q6); \
        Q0+=r0; Q1+=r1; Q2+=r2; Q3+=r3; Q4+=r4; Q5+=r5; Q6+=r6; Q7+=r7;                   \
        float u0=dppf<XOR2>(Q2), u3=dppf<XOR2>(Q1), u4=dppf<XOR2>(Q6), u7=dppf<XOR2>(Q5); \
        Q0+=u0; Q3+=u3; Q4+=u4; Q7+=u7;                                                   \
        float m0=dppf<MIR7>(Q3), m4=dppf<MIR7>(Q7);                                       \
        Q0+=m0; Q4+=m4;                                                                   \
        const float yv = lolane ? Q0 : Q4;                                                \
        const float av = fmaf(fs2, __builtin_amdgcn_rcpf(1.f + __expf(kae*yv)), fs3);     \
        const float gi = dppf<BC0>(av);                                                   \
        const float gf = dppf<BC1>(av);                                                   \
        const float gg = dppf<BC2>(av);                                                   \
        const float go = dppf<BC3>(av);                                                   \
        const bool rst = lolane ? ((SA)==0) : ((SB)==0);                                  \
        const bool upd = lolane ? (VA) : (VB);                                            \
        const float igv = gi * gg;                                                        \
        const float ccn = rst ? igv : fmaf(gf, CC, igv);                                  \
        CC = upd ? ccn : CC;                                                              \
        HN = go * tanh_f(CC);                                                             \
    }

__device__ __forceinline__ float xsel4(float x0, float x1, float x2, float x3, int q2) {
    return (q2 & 2) ? ((q2 & 1) ? x3 : x2) : ((q2 & 1) ? x1 : x0);
}

// General (prologue) x-sourcing. Every outr read is row (w+s-8)&7 == (p-8)&7.
__device__ __forceinline__ float xload(const float* trajS, const float (*outr)[2],
                                       int w, int s, int q2) {
    float x0, x1, x2, x3;
    if (w == 0) {
        x0 = trajS[s*4+0]; x1 = trajS[s*4+1]; x2 = trajS[s*4+2]; x3 = trajS[s*4+3];
    } else if (w < 8) {
        if (s < 8 - w) {
            const int tt = w + s;
            x0 = trajS[tt*4+0]; x1 = trajS[tt*4+1]; x2 = trajS[tt*4+2]; x3 = trajS[tt*4+3];
        } else {
            const int tc = 2*w + s - 1;
            const int jo2 = (w + s - 8) & 7;
            x0 = trajS[tc*4+0]; x1 = trajS[tc*4+1];
            x2 = outr[jo2][0];  x3 = outr[jo2][1];
        }
    } else {
        const int tc = w + s;
        const int jo2 = (w + s) & 7;
        x0 = trajS[tc*4+0]; x1 = trajS[tc*4+1];
        x2 = outr[jo2][0];  x3 = outr[jo2][1];
    }
    return xsel4(x0, x1, x2, x3, q2);
}

// 2 blocks per row. SAME-XCD PAIRING: row = bid&63, half = bid>>6 (pair r, r+64
// both == r mod 8 -> same XCD under round-robin; perf heuristic only).
// Exchange = out[p-8] as TWO tagged u64 atomics {tag=p+1, f32}; ONE spinner/block.
__global__ __launch_bounds__(512) __attribute__((amdgpu_waves_per_eu(2, 2)))
void or_lstm_coop(const float* __restrict__ traj,
                  const float* __restrict__ Wih0, const float* __restrict__ Whh0,
                  const float* __restrict__ bih0, const float* __restrict__ bhh0,
                  const float* __restrict__ Wih1, const float* __restrict__ Whh1,
                  const float* __restrict__ bih1, const float* __restrict__ bhh1,
                  const float* __restrict__ Wlin, const float* __restrict__ blin,
                  float* __restrict__ out, u64* __restrict__ ring)
{
    const int bid  = blockIdx.x;
    const int row  = bid & 63;
    const int half = bid >> 6;        // 0: slots 0-3, 1: slots 4-7  (pair on same XCD)
    const int tid  = threadIdx.x;     // = j*8 + idx
    const int j    = tid >> 3;
    const int idx  = tid & 7;
    const int q2   = idx & 3;

    __shared__ __align__(16) float trajS[256 * 4];
    __shared__ __align__(16) float X0[2][4][64];   // [parity][local slot][j]
    __shared__ __align__(16) float X1[2][4][64];
    __shared__ float outr[8][2];                   // full ring, mirrored in both blocks

    if (tid < 256)
        ((f4*)trajS)[tid] = ((const f4*)(traj + (size_t)row * 256 * 4))[tid];
    ((float*)X0)[tid] = 0.f;                       // 2*4*64 = 512 floats each
    ((float*)X1)[tid] = 0.f;

    // ---- gate-permuted weight slices as v2 pairs (identical in both blocks) ----
    const int jo = j * 64 + idx * 8;
    const int v0 = q2, v1 = 1 ^ q2, v2 = 2 ^ q2, v3 = 3 ^ q2;
    LDW2(W0, Whh0, v0) LDW2(W1, Whh0, v1) LDW2(W2, Whh0, v2) LDW2(W3, Whh0, v3)
    LDW2(U0, Wih1, v0) LDW2(U1, Wih1, v1) LDW2(U2, Wih1, v2) LDW2(U3, Wih1, v3)
    LDW2(V0, Whh1, v0) LDW2(V1, Whh1, v1) LDW2(V2, Whh1, v2) LDW2(V3, Whh1, v3)
    OPQW(W0) OPQW(W1) OPQW(W2) OPQW(W3)
    OPQW(U0) OPQW(U1) OPQW(U2) OPQW(U3)
    OPQW(V0) OPQW(V1) OPQW(V2) OPQW(V3)

    float wx0 = (idx < 4) ? Wih0[v0*256 + j*4 + q2] : 0.f;
    float wx1 = (idx < 4) ? Wih0[v1*256 + j*4 + q2] : 0.f;
    float wx2 = (idx < 4) ? Wih0[v2*256 + j*4 + q2] : 0.f;
    float wx3 = (idx < 4) ? Wih0[v3*256 + j*4 + q2] : 0.f;
    float bb00 = (idx == 0) ? (bih0[0*64+j] + bhh0[0*64+j]) : 0.f;
    float bb01 = (idx == 0) ? (bih0[1*64+j] + bhh0[1*64+j]) : 0.f;
    float bb02 = (idx == 0) ? (bih0[2*64+j] + bhh0[2*64+j]) : 0.f;
    float bb03 = (idx == 0) ? (bih0[3*64+j] + bhh0[3*64+j]) : 0.f;
    float bb10 = (idx == 0) ? (bih1[0*64+j] + bhh1[0*64+j]) : 0.f;
    float bb11 = (idx == 0) ? (bih1[1*64+j] + bhh1[1*64+j]) : 0.f;
    float bb12 = (idx == 0) ? (bih1[2*64+j] + bhh1[2*64+j]) : 0.f;
    float bb13 = (idx == 0) ? (bih1[3*64+j] + bhh1[3*64+j]) : 0.f;
    OPQ1(wx0) OPQ1(wx1) OPQ1(wx2) OPQ1(wx3)
    OPQ1(bb00) OPQ1(bb01) OPQ1(bb02) OPQ1(bb03)
    OPQ1(bb10) OPQ1(bb11) OPQ1(bb12) OPQ1(bb13)

    const float kae = (q2 == 2) ? -2.f : -1.f;
    const float fs2 = (q2 == 2) ?  2.f :  1.f;
    const float fs3 = (q2 == 2) ? -1.f :  0.f;

    // epilogue weights: wave 0 computes BOTH output components
    float wl0 = 0.f, wl1 = 0.f;
    if (tid < 64) { wl0 = Wlin[tid]; wl1 = Wlin[64 + tid]; }
    const float bl0 = blin[0], bl1 = blin[1];

    const bool lolane = (idx < 4);
    float cc0[2] = {0.f, 0.f};    // L0 cell per local pair (A in quad0, B in quad1)
    float cc1[2] = {0.f, 0.f};

    __syncthreads();

    for (int p = 0; p < NPH2; ++p) {
        const int par = p & 1;
        const float* X0r = &X0[par ^ 1][0][idx * 8];
        const float* X1r = &X1[par ^ 1][0][idx * 8];
        float* X0w = &X0[par][0][j];
        float* X1w = &X1[par][0][j];

        float QM[2][8];   // L0 bias + Whh0.h0 accumulators, live across barriers

        // ======== REGION A: L1(p-1) full + L0(p) h-part, own 2 pairs ========
        #pragma unroll
        for (int P = 0; P < 2; ++P) {
            const int cA = 4*half + 2*P, cB = cA + 1;    // global slots
            const int lA = 2*P,          lB = lA + 1;    // local slots
            const int sA0 = (p - cA) & 7,     sB0 = (p - cB) & 7;
            const int sA1 = (p - 1 - cA) & 7, sB1 = (p - 1 - cB) & 7;
            const bool vA1 = (unsigned)(p - 1 - sA1) < (unsigned)NW;
            const bool vB1 = (unsigned)(p - 1 - sB1) < (unsigned)NW;

            // h0(p-1) slices (v2) — feed both L0 W-dot and L1 U-dot
            const v4f hAa = *(const v4f*)(X0r + lA*64), hAb = *(const v4f*)(X0r + lA*64 + 4);
            const v4f hBa = *(const v4f*)(X0r + lB*64), hBb = *(const v4f*)(X0r + lB*64 + 4);
            const v2f hA0 = LO2(hAa), hA1 = HI2(hAa), hA2 = LO2(hAb), hA3 = HI2(hAb);
            const v2f hB0 = LO2(hBa), hB1 = HI2(hBa), hB2 = LO2(hBb), hB3 = HI2(hBb);

            {   // L0 main gates (bias + Whh0.h0; x added in region C) — packed
                v2f a0 = {bb00, 0.f}, a1 = {bb01, 0.f}, a2 = {bb02, 0.f}, a3 = {bb03, 0.f};
                v2f a4 = {bb00, 0.f}, a5 = {bb01, 0.f}, a6 = {bb02, 0.f}, a7 = {bb03, 0.f};
                if (sA0 != 0) {
                    DOTG(W0, hA0,hA1,hA2,hA3, a0)
                    DOTG(W1, hA0,hA1,hA2,hA3, a1)
                    DOTG(W2, hA0,hA1,hA2,hA3, a2)
                    DOTG(W3, hA0,hA1,hA2,hA3, a3)
                }
                if (sB0 != 0) {
                    DOTG(W0, hB0,hB1,hB2,hB3, a4)
                    DOTG(W1, hB0,hB1,hB2,hB3, a5)
                    DOTG(W2, hB0,hB1,hB2,hB3, a6)
                    DOTG(W3, hB0,hB1,hB2,hB3, a7)
                }
                QM[P][0]=a0.x+a0.y; QM[P][1]=a1.x+a1.y; QM[P][2]=a2.x+a2.y; QM[P][3]=a3.x+a3.y;
                QM[P][4]=a4.x+a4.y; QM[P][5]=a5.x+a5.y; QM[P][6]=a6.x+a6.y; QM[P][7]=a7.x+a7.y;
            }

            {   // L1 gates: Wih1.h0(p-1) (reuse h slices) + Whh1.h1(p-2) — packed
                v2f p0 = {bb10, 0.f}, p1 = {bb11, 0.f}, p2 = {bb12, 0.f}, p3 = {bb13, 0.f};
                v2f p4 = {bb10, 0.f}, p5 = {bb11, 0.f}, p6 = {bb12, 0.f}, p7 = {bb13, 0.f};
                DOTG(U0, hA0,hA1,hA2,hA3, p0)
                DOTG(U1, hA0,hA1,hA2,hA3, p1)
                DOTG(U2, hA0,hA1,hA2,hA3, p2)
                DOTG(U3, hA0,hA1,hA2,hA3, p3)
                DOTG(U0, hB0,hB1,hB2,hB3, p4)
                DOTG(U1, hB0,hB1,hB2,hB3, p5)
                DOTG(U2, hB0,hB1,hB2,hB3, p6)
                DOTG(U3, hB0,hB1,hB2,hB3, p7)
                if (sA1 != 0) {
                    const v4f eAa = *(const v4f*)(X1r + lA*64), eAb = *(const v4f*)(X1r + lA*64 + 4);
                    const v2f eA0 = LO2(eAa), eA1 = HI2(eAa), eA2 = LO2(eAb), eA3 = HI2(eAb);
                    DOTG(V0, eA0,eA1,eA2,eA3, p0)
                    DOTG(V1, eA0,eA1,eA2,eA3, p1)
                    DOTG(V2, eA0,eA1,eA2,eA3, p2)
                    DOTG(V3, eA0,eA1,eA2,eA3, p3)
                }
                if (sB1 != 0) {
                    const v4f eBa = *(const v4f*)(X1r + lB*64), eBb = *(const v4f*)(X1r + lB*64 + 4);
                    const v2f eB0 = LO2(eBa), eB1 = HI2(eBa), eB2 = LO2(eBb), eB3 = HI2(eBb);
                    DOTG(V0, eB0,eB1,eB2,eB3, p4)
                    DOTG(V1, eB0,eB1,eB2,eB3, p5)
                    DOTG(V2, eB0,eB1,eB2,eB3, p6)
                    DOTG(V3, eB0,eB1,eB2,eB3, p7)
                }
                float Q0 = p0.x+p0.y, Q1 = p1.x+p1.y, Q2 = p2.x+p2.y, Q3 = p3.x+p3.y;
                float Q4 = p4.x+p4.y, Q5 = p5.x+p5.y, Q6 = p6.x+p6.y, Q7 = p7.x+p7.y;
                float hn1;
                TAIL8(cc1[P], sA1, sB1, vA1, vB1, hn1)
                if (vA1 && idx == 0) X1w[lA*64] = hn1;
                if (vB1 && idx == 4) X1w[lB*64] = hn1;
            }
        }
        __syncthreads();                 // bar1: h1(p-1) visible (incl. finishing window p-8)

        // ======== REGION B: out[p-8] — produce (owner) / receive (single spinner) ========
        if (p >= 8) {
            const int w1 = p - 8;
            const int gs = p & 7;                                  // finishing global slot
            u64* rp = ring + ((size_t)row * 16 + (p & 15)) * 2;
            const unsigned tag = (unsigned)(p + 1);
            if ((gs >> 2) == half) {
                // producer: wave 0 computes both Wlin dots from own X1 slot
                if (tid < 64) {
                    const float hval = X1[par][gs & 3][tid];
                    float r0 = wl0 * hval, r1 = wl1 * hval;
                    #pragma unroll
                    for (int off = 32; off > 0; off >>= 1) {
                        r0 += __shfl_down(r0, off);
                        r1 += __shfl_down(r1, off);
                    }
                    if (tid == 0) {
                        const float prev0 = w1 ? outr[(w1-1) & 7][0] : trajS[7*4+2];
                        const float prev1 = w1 ? outr[(w1-1) & 7][1] : trajS[7*4+3];
                        const float o0 = prev0 + r0 + bl0;
                        const float o1 = prev1 + r1 + bl1;
                        outr[w1 & 7][0] = o0; outr[w1 & 7][1] = o1;
                        out[((size_t)row * NW + w1) * 2 + 0] = o0;
                        out[((size_t)row * NW + w1) * 2 + 1] = o1;
                        const u64 pk0 = ((u64)tag << 32) | (u64)__float_as_uint(o0);
                        const u64 pk1 = ((u64)tag << 32) | (u64)__float_as_uint(o1);
                        __hip_atomic_store(&rp[0], pk0, __ATOMIC_RELEASE, __HIP_MEMORY_SCOPE_AGENT);
                        __hip_atomic_store(&rp[1], pk1, __ATOMIC_RELEASE, __HIP_MEMORY_SCOPE_AGENT);
                    }
                }
            } else {
                // consumer: exactly ONE thread spins, fills the LDS ring
                if (tid == 0) {
                    u64 va, vb;
                    do { va = __hip_atomic_load(&rp[0], __ATOMIC_ACQUIRE, __HIP_MEMORY_SCOPE_AGENT);
                    } while ((unsigned)(va >> 32) != tag);
                    do { vb = __hip_atomic_load(&rp[1], __ATOMIC_ACQUIRE, __HIP_MEMORY_SCOPE_AGENT);
                    } while ((unsigned)(vb >> 32) != tag);
                    outr[w1 & 7][0] = __uint_as_float((unsigned)va);
                    outr[w1 & 7][1] = __uint_as_float((unsigned)vb);
                }
            }
        }
        __syncthreads();                 // bar2: outr[(p-8)&7] visible

        // ======== REGION C: rank-2 x-feedback + L0 TAILs ========
        float xs0, xs1, xs2, xs3;
        if (p >= 15) {
            const float xc = xsel4(trajS[p*4+0], trajS[p*4+1],
                                   outr[p & 7][0], outr[p & 7][1], q2);
            xs0 = xs1 = xs2 = xs3 = xc;
        } else {
            float t[4];
            #pragma unroll
            for (int c = 0; c < 4; ++c) {
                const int g = 4*half + c;
                const int s = (p - g) & 7;
                const int w = p - s;
                t[c] = ((unsigned)w < (unsigned)NW) ? xload(trajS, outr, w, s, q2) : 0.f;
            }
            xs0 = t[0]; xs1 = t[1]; xs2 = t[2]; xs3 = t[3];
        }
        #pragma unroll
        for (int P = 0; P < 2; ++P) {
            const int cA = 4*half + 2*P, cB = cA + 1;
            const int lA = 2*P,          lB = lA + 1;
            const int sA0 = (p - cA) & 7, sB0 = (p - cB) & 7;
            const bool vA0 = (unsigned)(p - sA0) < (unsigned)NW;
            const bool vB0 = (unsigned)(p - sB0) < (unsigned)NW;
            const float xA = P ? xs2 : xs0;
            const float xB = P ? xs3 : xs1;
            float Q0 = fmaf(wx0, xA, QM[P][0]);
            float Q1 = fmaf(wx1, xA, QM[P][1]);
            float Q2 = fmaf(wx2, xA, QM[P][2]);
            float Q3 = fmaf(wx3, xA, QM[P][3]);
            float Q4 = fmaf(wx0, xB, QM[P][4]);
            float Q5 = fmaf(wx1, xB, QM[P][5]);
            float Q6 = fmaf(wx2, xB, QM[P][6]);
            float Q7 = fmaf(wx3, xB, QM[P][7]);
            float hn0;
            TAIL8(cc0[P], sA0, sB0, vA0, vB0, hn0)
            if (vA0 && idx == 0) X0w[lA*64] = hn0;
            if (vB0 && idx == 4) X0w[lB*64] = hn0;
        }
        __syncthreads();                 // bar3: h0(p) visible for next phase
    }

    // ---- final hidden/cell state: window NW-1 = global slot 7 -> half 1, local slot 3 ----
    // h0 final written phase 254 (par 0); h1 final phase 255 (par 1). Pair P=1, B-side -> hi quad.
    if (half == 1 && idx == 4) {
        float* hn = out + (size_t)NB * NW * 2;
        float* cn = hn + 2 * NB * 64;
        hn[(0 * NB + row) * 64 + j] = X0[0][3][j];
        hn[(1 * NB + row) * 64 + j] = X1[1][3][j];
        cn[(0 * NB + row) * 64 + j] = cc0[1];
        cn[(1 * NB + row) * 64 + j] = cc1[1];
    }
}

extern "C" void kernel_launch(void* const* d_in, const int* in_sizes, int n_in,
                              void* d_out, int out_size, void* d_ws, size_t ws_size,
                              hipStream_t stream) {
    const float* traj = (const float*)d_in[0];
    const float* Wih0 = (const float*)d_in[1];
    const float* Whh0 = (const float*)d_in[2];
    const float* bih0 = (const float*)d_in[3];
    const float* bhh0 = (const float*)d_in[4];
    const float* Wih1 = (const float*)d_in[5];
    const float* Whh1 = (const float*)d_in[6];
    const float* bih1 = (const float*)d_in[7];
    const float* bhh1 = (const float*)d_in[8];
    const float* Wlin = (const float*)d_in[9];
    const float* blin = (const float*)d_in[10];
    float* out = (float*)d_out;

    // workspace: ring = u64[64 rows][16 slots][2] (16 KB), tag-embedded values.
    u64* ring = (u64*)d_ws;
    // zero tags every launch (graph-captured -> re-runs on every replay); first tag used is 9.
    hipMemsetAsync(d_ws, 0, (size_t)NB * 16 * 2 * sizeof(u64), stream);

    void* kargs[] = { (void*)&traj, (void*)&Wih0, (void*)&Whh0, (void*)&bih0, (void*)&bhh0,
                      (void*)&Wih1, (void*)&Whh1, (void*)&bih1, (void*)&bhh1,
                      (void*)&Wlin, (void*)&blin, (void*)&out, (void*)&ring };
    hipLaunchCooperativeKernel((const void*)or_lstm_coop, dim3(NB * 2), dim3(512),
                               kargs, 0, stream);
}